// Round 1
// baseline (495.148 us; speedup 1.0000x reference)
//
#include <hip/hip_runtime.h>
#include <math.h>

// Problem constants
#define S 512
#define C 384
#define H 12
#define SQK 16
#define SV 16
#define PQK 4
#define PV 8
#define SCALAR_SCALE 0.25f   // 16^-0.5
#define NEG_LOGIT (-10000.0f)

// X layout per row (1152 cols): [qs 192 | ks 192 | vs 192 | qp 144 | kp 144 | vp 288]
#define XQ 0
#define XK 192
#define XV 384
#define XQP 576
#define XKP 720
#define XVP 864
#define XCOLS 1152

// Fused dims
#define DQK 28   // 16 scalar + 12 weighted point
#define DV 40    // 16 scalar + 24 point

// ---------------------------------------------------------------------------
// Generic tiled fp32 GEMM: C[m, colOff+n] = (A[m,:K] @ B[:K, n]) + bias[n]
// optionally zeroing rows where rowMask[m]==0.  BM=BN=64, BK=16, 256 threads,
// 4x4 micro-tile per thread.  Requires M%64==0, K%16==0, N%4==0, lda%4==0,
// ldb%4==0 (all hold here).
// ---------------------------------------------------------------------------
__global__ __launch_bounds__(256)
void gemm_bias(const float* __restrict__ A, int lda,
               const float* __restrict__ B, int ldb,
               const float* __restrict__ bias,
               float* __restrict__ Cc, int ldc, int colOff,
               int M, int N, int K,
               const int* __restrict__ rowMask)
{
    __shared__ float As[16][65];
    __shared__ float Bs[16][65];
    const int tid = threadIdx.x;
    const int m0 = blockIdx.y * 64;
    const int n0 = blockIdx.x * 64;
    const int ty = tid >> 4;     // 0..15
    const int tx = tid & 15;     // 0..15

    float acc[4][4] = {};

    for (int k0 = 0; k0 < K; k0 += 16) {
        // A tile: rows m0..m0+63, k k0..k0+15 ; store transposed As[k][m]
        {
            int r = tid >> 2;            // 0..63
            int c = (tid & 3) * 4;       // 0,4,8,12
            const float4 v = *(const float4*)(A + (size_t)(m0 + r) * lda + k0 + c);
            As[c + 0][r] = v.x; As[c + 1][r] = v.y;
            As[c + 2][r] = v.z; As[c + 3][r] = v.w;
        }
        // B tile: k k0..k0+15, cols n0..n0+63
        {
            int r = tid >> 4;            // 0..15
            int c = (tid & 15) * 4;      // 0..60
            int n = n0 + c;
            float4 v = make_float4(0.f, 0.f, 0.f, 0.f);
            if (n + 3 < N)               // N%4==0 and n%4==0 -> never partial
                v = *(const float4*)(B + (size_t)(k0 + r) * ldb + n);
            Bs[r][c + 0] = v.x; Bs[r][c + 1] = v.y;
            Bs[r][c + 2] = v.z; Bs[r][c + 3] = v.w;
        }
        __syncthreads();
        #pragma unroll
        for (int k = 0; k < 16; ++k) {
            float a[4], b[4];
            #pragma unroll
            for (int i = 0; i < 4; ++i) a[i] = As[k][ty * 4 + i];
            #pragma unroll
            for (int j = 0; j < 4; ++j) b[j] = Bs[k][tx * 4 + j];
            #pragma unroll
            for (int i = 0; i < 4; ++i)
                #pragma unroll
                for (int j = 0; j < 4; ++j)
                    acc[i][j] += a[i] * b[j];
        }
        __syncthreads();
    }

    #pragma unroll
    for (int i = 0; i < 4; ++i) {
        int m = m0 + ty * 4 + i;
        float msk = 1.0f;
        if (rowMask) msk = rowMask[m] ? 1.0f : 0.0f;
        #pragma unroll
        for (int j = 0; j < 4; ++j) {
            int n = n0 + tx * 4 + j;
            if (n < N)
                Cc[(size_t)m * ldc + colOff + n] = (acc[i][j] + bias[n]) * msk;
        }
    }
}

// ---------------------------------------------------------------------------
// Build fused QH/KH/V and key bias from projections X + rotations/translations.
// One thread per (s, h).
//   QH[h][s][0:16]  = qs * 0.25 ; QH[..][16+p*3+i] = softplus(w[h][p]) * qpg_i
//   KH[h][s][0:16]  = ks        ; KH[..][16+p*3+i] = kpg_i
//   V [h][s][0:16]  = vs        ; V [..][16+p*3+i] = vpg_i
//   kb[h][s]        = -0.5 * sum_p w_hp * |kpg|^2
// ---------------------------------------------------------------------------
__global__ __launch_bounds__(256)
void ipa_points(const float* __restrict__ X,
                const float* __restrict__ rot,      // [S][3][3]
                const float* __restrict__ trans,    // [S][3]
                const float* __restrict__ pw,       // [H][PQK]
                float* __restrict__ QH, float* __restrict__ KH,
                float* __restrict__ VH, float* __restrict__ kb)
{
    int idx = blockIdx.x * blockDim.x + threadIdx.x;
    if (idx >= S * H) return;
    int s = idx / H;
    int h = idx - s * H;

    float R[9], t[3];
    #pragma unroll
    for (int i = 0; i < 9; ++i) R[i] = rot[s * 9 + i];
    #pragma unroll
    for (int i = 0; i < 3; ++i) t[i] = trans[s * 3 + i];

    float spw[PQK];
    #pragma unroll
    for (int p = 0; p < PQK; ++p)
        spw[p] = log1pf(__expf(pw[h * PQK + p]));

    const float* xr = X + (size_t)s * XCOLS;
    float* qh = QH + ((size_t)h * S + s) * DQK;
    float* kh = KH + ((size_t)h * S + s) * DQK;
    float* vh = VH + ((size_t)h * S + s) * DV;

    #pragma unroll
    for (int d = 0; d < 16; ++d) qh[d] = xr[XQ + h * 16 + d] * SCALAR_SCALE;
    #pragma unroll
    for (int d = 0; d < 16; ++d) kh[d] = xr[XK + h * 16 + d];
    #pragma unroll
    for (int d = 0; d < 16; ++d) vh[d] = xr[XV + h * 16 + d];

    float knorm = 0.0f;
    #pragma unroll
    for (int p = 0; p < PQK; ++p) {
        const float* q = xr + XQP + h * (PQK * 3) + p * 3;
        const float* k = xr + XKP + h * (PQK * 3) + p * 3;
        #pragma unroll
        for (int i = 0; i < 3; ++i) {
            float qg = R[i * 3 + 0] * q[0] + R[i * 3 + 1] * q[1] + R[i * 3 + 2] * q[2] + t[i];
            float kg = R[i * 3 + 0] * k[0] + R[i * 3 + 1] * k[1] + R[i * 3 + 2] * k[2] + t[i];
            qh[16 + p * 3 + i] = spw[p] * qg;
            kh[16 + p * 3 + i] = kg;
            knorm += spw[p] * kg * kg;
        }
    }
    kb[(size_t)h * S + s] = -0.5f * knorm;

    #pragma unroll
    for (int p = 0; p < PV; ++p) {
        const float* v = xr + XVP + h * (PV * 3) + p * 3;
        #pragma unroll
        for (int i = 0; i < 3; ++i) {
            float vg = R[i * 3 + 0] * v[0] + R[i * 3 + 1] * v[1] + R[i * 3 + 2] * v[2] + t[i];
            vh[16 + p * 3 + i] = vg;
        }
    }
}

// ---------------------------------------------------------------------------
// Attention: one wave per (head h, query row i).  Block = 4 waves.
// logits_ij = QH_i . KH_j + kb_j  (qn_i term dropped: softmax-invariant),
// masked keys -> -1e4.  Softmax + PV in-register, butterfly reduces.
// Epilogue applies R_i^T to (pog - t), writes into combined[S][576].
// ---------------------------------------------------------------------------
__global__ __launch_bounds__(256)
void ipa_attn(const float* __restrict__ QH, const float* __restrict__ KH,
              const float* __restrict__ VH, const float* __restrict__ kb,
              const int* __restrict__ valid,
              const float* __restrict__ rot, const float* __restrict__ trans,
              float* __restrict__ combined)
{
    const int h = blockIdx.x;                       // 0..11
    const int wave = threadIdx.x >> 6;              // 0..3
    const int lane = threadIdx.x & 63;
    const int i = blockIdx.y * 4 + wave;            // query row

    // broadcast-load fused query
    const float* qh = QH + ((size_t)h * S + i) * DQK;
    float q[DQK];
    #pragma unroll
    for (int d = 0; d < DQK; ++d) q[d] = qh[d];

    // pass 1: logits for keys j = t*64 + lane
    float logit[8];
    float mx = -3.0e38f;
    #pragma unroll
    for (int t = 0; t < 8; ++t) {
        int j = t * 64 + lane;
        const float* kh = KH + ((size_t)h * S + j) * DQK;
        float dot = kb[(size_t)h * S + j];
        #pragma unroll
        for (int d = 0; d < DQK; ++d) dot += q[d] * kh[d];
        logit[t] = valid[j] ? dot : NEG_LOGIT;
        mx = fmaxf(mx, logit[t]);
    }
    #pragma unroll
    for (int off = 32; off >= 1; off >>= 1)
        mx = fmaxf(mx, __shfl_xor(mx, off, 64));

    float sum = 0.0f;
    #pragma unroll
    for (int t = 0; t < 8; ++t) {
        logit[t] = __expf(logit[t] - mx);
        sum += logit[t];
    }
    #pragma unroll
    for (int off = 32; off >= 1; off >>= 1)
        sum += __shfl_xor(sum, off, 64);
    const float inv = 1.0f / sum;

    // pass 2: PV accumulate (unnormalized)
    float acc[DV] = {};
    #pragma unroll
    for (int t = 0; t < 8; ++t) {
        int j = t * 64 + lane;
        const float* vh = VH + ((size_t)h * S + j) * DV;
        float p = logit[t];
        #pragma unroll
        for (int d = 0; d < DV; ++d) acc[d] += p * vh[d];
    }
    #pragma unroll
    for (int d = 0; d < DV; ++d)
        #pragma unroll
        for (int off = 32; off >= 1; off >>= 1)
            acc[d] += __shfl_xor(acc[d], off, 64);
    // every lane now holds full sums

    float* crow = combined + (size_t)i * 576;
    if (lane < 16)
        crow[h * 16 + lane] = acc[lane] * inv;

    if (lane < 8) {
        float R[9], t_[3];
        #pragma unroll
        for (int a = 0; a < 9; ++a) R[a] = rot[i * 9 + a];
        #pragma unroll
        for (int a = 0; a < 3; ++a) t_[a] = trans[i * 3 + a];
        int p = lane;
        float d0 = acc[16 + p * 3 + 0] * inv - t_[0];
        float d1 = acc[16 + p * 3 + 1] * inv - t_[1];
        float d2 = acc[16 + p * 3 + 2] * inv - t_[2];
        // pol = R^T d
        float pol0 = R[0] * d0 + R[3] * d1 + R[6] * d2;
        float pol1 = R[1] * d0 + R[4] * d1 + R[7] * d2;
        float pol2 = R[2] * d0 + R[5] * d1 + R[8] * d2;
        crow[192 + h * 24 + p * 3 + 0] = pol0;
        crow[192 + h * 24 + p * 3 + 1] = pol1;
        crow[192 + h * 24 + p * 3 + 2] = pol2;
        crow[480 + h * 8 + p] = sqrtf(pol0 * pol0 + pol1 * pol1 + pol2 * pol2);
    }
}

// ---------------------------------------------------------------------------
extern "C" void kernel_launch(void* const* d_in, const int* in_sizes, int n_in,
                              void* d_out, int out_size, void* d_ws, size_t ws_size,
                              hipStream_t stream)
{
    const float* single = (const float*)d_in[0];
    const float* rot    = (const float*)d_in[1];
    const float* trans  = (const float*)d_in[2];
    const float* Wq_s   = (const float*)d_in[3];
    const float* bq_s   = (const float*)d_in[4];
    const float* Wk_s   = (const float*)d_in[5];
    const float* bk_s   = (const float*)d_in[6];
    const float* Wv_s   = (const float*)d_in[7];
    const float* bv_s   = (const float*)d_in[8];
    const float* Wq_p   = (const float*)d_in[9];
    const float* bq_p   = (const float*)d_in[10];
    const float* Wk_p   = (const float*)d_in[11];
    const float* bk_p   = (const float*)d_in[12];
    const float* Wv_p   = (const float*)d_in[13];
    const float* bv_p   = (const float*)d_in[14];
    const float* pw     = (const float*)d_in[15];
    const float* Wo     = (const float*)d_in[16];
    const float* bo     = (const float*)d_in[17];
    const int*   valid  = (const int*)d_in[18];

    float* ws = (float*)d_ws;
    float* X        = ws;                          // 512*1152
    float* QH       = X  + (size_t)S * XCOLS;      // 12*512*28
    float* KH       = QH + (size_t)H * S * DQK;    // 12*512*28
    float* VH       = KH + (size_t)H * S * DQK;    // 12*512*40
    float* kbb      = VH + (size_t)H * S * DV;     // 12*512
    float* combined = kbb + (size_t)H * S;         // 512*576

    dim3 blk(256);

    // Projections into X (M=512, K=384)
    gemm_bias<<<dim3(3, 8), blk, 0, stream>>>(single, C, Wq_s, 192, bq_s, X, XCOLS, XQ,  S, 192, C, nullptr);
    gemm_bias<<<dim3(3, 8), blk, 0, stream>>>(single, C, Wk_s, 192, bk_s, X, XCOLS, XK,  S, 192, C, nullptr);
    gemm_bias<<<dim3(3, 8), blk, 0, stream>>>(single, C, Wv_s, 192, bv_s, X, XCOLS, XV,  S, 192, C, nullptr);
    gemm_bias<<<dim3(3, 8), blk, 0, stream>>>(single, C, Wq_p, 144, bq_p, X, XCOLS, XQP, S, 144, C, nullptr);
    gemm_bias<<<dim3(3, 8), blk, 0, stream>>>(single, C, Wk_p, 144, bk_p, X, XCOLS, XKP, S, 144, C, nullptr);
    gemm_bias<<<dim3(5, 8), blk, 0, stream>>>(single, C, Wv_p, 288, bv_p, X, XCOLS, XVP, S, 288, C, nullptr);

    // Fused Q/K/V build with rotations
    ipa_points<<<dim3((S * H + 255) / 256), blk, 0, stream>>>(X, rot, trans, pw, QH, KH, VH, kbb);

    // Attention -> combined
    ipa_attn<<<dim3(H, S / 4), blk, 0, stream>>>(QH, KH, VH, kbb, valid, rot, trans, combined);

    // Output projection with query-row masking
    gemm_bias<<<dim3(6, 8), blk, 0, stream>>>(combined, 576, Wo, C, bo, (float*)d_out, C, 0, S, C, 576, valid);
}

// Round 6
// 192.548 us; speedup vs baseline: 2.5716x; 2.5716x over previous
//
#include <hip/hip_runtime.h>
#include <math.h>

// Problem constants
#define S 512
#define C 384
#define H 12
#define SCALAR_SCALE 0.25f   // 16^-0.5
#define NEG_LOGIT (-10000.0f)

// X layout per row (1152 cols): [qs 192 | ks 192 | vs 192 | qp 144 | kp 144 | vp 288]
#define XCOLS 1152
#define DQK 28   // fused logit dim: 16 scalar + 12 weighted point
#define DV 40    // fused value dim: 16 scalar + 24 global point

// ---------------------------------------------------------------------------
// Concat the 6 projection weight matrices into Wcat[384][1152] + bcat[1152].
// One float4 per thread, fully coalesced stores.
// ---------------------------------------------------------------------------
__global__ __launch_bounds__(256)
void wcat_kernel(const float* __restrict__ Wq_s, const float* __restrict__ bq_s,
                 const float* __restrict__ Wk_s, const float* __restrict__ bk_s,
                 const float* __restrict__ Wv_s, const float* __restrict__ bv_s,
                 const float* __restrict__ Wq_p, const float* __restrict__ bq_p,
                 const float* __restrict__ Wk_p, const float* __restrict__ bk_p,
                 const float* __restrict__ Wv_p, const float* __restrict__ bv_p,
                 float* __restrict__ Wcat, float* __restrict__ bcat)
{
    const int NW4 = 384 * (XCOLS / 4);
    int t = blockIdx.x * 256 + threadIdx.x;
    if (t < NW4) {
        int k = t / (XCOLS / 4);
        int col = (t - k * (XCOLS / 4)) * 4;
        const float* src;
        if      (col < 192) src = Wq_s + k * 192 + col;
        else if (col < 384) src = Wk_s + k * 192 + (col - 192);
        else if (col < 576) src = Wv_s + k * 192 + (col - 384);
        else if (col < 720) src = Wq_p + k * 144 + (col - 576);
        else if (col < 864) src = Wk_p + k * 144 + (col - 720);
        else                src = Wv_p + k * 288 + (col - 864);
        ((float4*)Wcat)[t] = *(const float4*)src;
    } else if (t < NW4 + XCOLS / 4) {
        int col = (t - NW4) * 4;
        const float* src;
        if      (col < 192) src = bq_s + col;
        else if (col < 384) src = bk_s + (col - 192);
        else if (col < 576) src = bv_s + (col - 384);
        else if (col < 720) src = bq_p + (col - 576);
        else if (col < 864) src = bk_p + (col - 720);
        else                src = bv_p + (col - 864);
        ((float4*)bcat)[t - NW4] = *(const float4*)src;
    }
}

// ---------------------------------------------------------------------------
// Tiled fp32 GEMM 64x64: C[m, n] = A[m,:K] @ B[:K, n] + bias[n].
// 256 threads, 4x4 micro-tile.  M%64==0, N%64==0, K%16==0.
// ---------------------------------------------------------------------------
__global__ __launch_bounds__(256)
void gemm64(const float* __restrict__ A, int lda,
            const float* __restrict__ B, int ldb,
            const float* __restrict__ bias,
            float* __restrict__ Cc, int ldc, int K)
{
    __shared__ float As[16][65];
    __shared__ float Bs[16][65];
    const int tid = threadIdx.x;
    const int m0 = blockIdx.y * 64;
    const int n0 = blockIdx.x * 64;
    const int ty = tid >> 4;
    const int tx = tid & 15;

    float acc[4][4] = {};

    for (int k0 = 0; k0 < K; k0 += 16) {
        {
            int r = tid >> 2;
            int c = (tid & 3) * 4;
            const float4 v = *(const float4*)(A + (size_t)(m0 + r) * lda + k0 + c);
            As[c + 0][r] = v.x; As[c + 1][r] = v.y;
            As[c + 2][r] = v.z; As[c + 3][r] = v.w;
        }
        {
            int r = tid >> 4;
            int c = (tid & 15) * 4;
            const float4 v = *(const float4*)(B + (size_t)(k0 + r) * ldb + n0 + c);
            Bs[r][c + 0] = v.x; Bs[r][c + 1] = v.y;
            Bs[r][c + 2] = v.z; Bs[r][c + 3] = v.w;
        }
        __syncthreads();
        #pragma unroll
        for (int k = 0; k < 16; ++k) {
            float a[4], b[4];
            #pragma unroll
            for (int i = 0; i < 4; ++i) a[i] = As[k][ty * 4 + i];
            #pragma unroll
            for (int j = 0; j < 4; ++j) b[j] = Bs[k][tx * 4 + j];
            #pragma unroll
            for (int i = 0; i < 4; ++i)
                #pragma unroll
                for (int j = 0; j < 4; ++j)
                    acc[i][j] += a[i] * b[j];
        }
        __syncthreads();
    }

    #pragma unroll
    for (int i = 0; i < 4; ++i) {
        int m = m0 + ty * 4 + i;
        #pragma unroll
        for (int j = 0; j < 4; ++j) {
            int n = n0 + tx * 4 + j;
            Cc[(size_t)m * ldc + n] = acc[i][j] + bias[n];
        }
    }
}

// ---------------------------------------------------------------------------
// 32x32-tile GEMM for the output projection (more blocks for this small
// shape): out[m,n] = (combined[m,:576] @ Wo[:,n] + bo[n]) * rowMask[m]
// ---------------------------------------------------------------------------
__global__ __launch_bounds__(256)
void gemm_out(const float* __restrict__ A, int lda,
              const float* __restrict__ B, int ldb,
              const float* __restrict__ bias,
              float* __restrict__ Cc, int ldc, int K,
              const int* __restrict__ rowMask)
{
    __shared__ float As[16][33];
    __shared__ float Bs[16][33];
    const int tid = threadIdx.x;
    const int m0 = blockIdx.y * 32;
    const int n0 = blockIdx.x * 32;
    const int ty = tid >> 4;     // 0..15
    const int tx = tid & 15;     // 0..15

    float acc[2][2] = {};

    for (int k0 = 0; k0 < K; k0 += 16) {
        {
            int r = tid >> 3;            // 0..31
            int c = (tid & 7) * 2;       // 0..14
            const float2 v = *(const float2*)(A + (size_t)(m0 + r) * lda + k0 + c);
            As[c + 0][r] = v.x; As[c + 1][r] = v.y;
        }
        {
            int r = tid >> 4;            // 0..15
            int c = (tid & 15) * 2;      // 0..30
            const float2 v = *(const float2*)(B + (size_t)(k0 + r) * ldb + n0 + c);
            Bs[r][c + 0] = v.x; Bs[r][c + 1] = v.y;
        }
        __syncthreads();
        #pragma unroll
        for (int k = 0; k < 16; ++k) {
            float a0 = As[k][ty * 2], a1 = As[k][ty * 2 + 1];
            float b0 = Bs[k][tx * 2], b1 = Bs[k][tx * 2 + 1];
            acc[0][0] += a0 * b0; acc[0][1] += a0 * b1;
            acc[1][0] += a1 * b0; acc[1][1] += a1 * b1;
        }
        __syncthreads();
    }

    #pragma unroll
    for (int i = 0; i < 2; ++i) {
        int m = m0 + ty * 2 + i;
        float msk = rowMask[m] ? 1.0f : 0.0f;
        #pragma unroll
        for (int j = 0; j < 2; ++j) {
            int n = n0 + tx * 2 + j;
            Cc[(size_t)m * ldc + n] = (acc[i][j] + bias[n]) * msk;
        }
    }
}

// ---------------------------------------------------------------------------
// Build fused Q/K/V in d-major float4 layouts + key bias.
// Thread per (h, s), s fastest -> all writes coalesced.
//   Q4[h][7][512]  : 16 scalar*0.25  then 12 dims of softplus(w)*qpg
//   K4[h][7][512]  : 16 scalar       then 12 dims of kpg
//   V4[h][10][512] : 16 scalar       then 24 dims of vpg
//   kb[h][512]     : -0.5 * sum_p w_hp |kpg_p|^2   (query-side norm cancels)
// ---------------------------------------------------------------------------
__global__ __launch_bounds__(256)
void ipa_points(const float* __restrict__ X,
                const float* __restrict__ rot,      // [S][3][3]
                const float* __restrict__ trans,    // [S][3]
                const float* __restrict__ pw,       // [H][4]
                float4* __restrict__ Q4, float4* __restrict__ K4,
                float4* __restrict__ V4, float* __restrict__ kb)
{
    int idx = blockIdx.x * 256 + threadIdx.x;   // 0..6143
    int h = idx >> 9;
    int s = idx & 511;

    float R[9], t[3];
    #pragma unroll
    for (int i = 0; i < 9; ++i) R[i] = rot[s * 9 + i];
    #pragma unroll
    for (int i = 0; i < 3; ++i) t[i] = trans[s * 3 + i];

    float spw[4];
    #pragma unroll
    for (int p = 0; p < 4; ++p)
        spw[p] = log1pf(__expf(pw[h * 4 + p]));

    const float4* xr4 = (const float4*)(X + (size_t)s * XCOLS);

    float qv[DQK], kv[DQK], vv[DV];
    // scalar parts
    #pragma unroll
    for (int g = 0; g < 4; ++g) {
        float4 a = xr4[h * 4 + g];               // qs
        qv[g * 4 + 0] = a.x * SCALAR_SCALE; qv[g * 4 + 1] = a.y * SCALAR_SCALE;
        qv[g * 4 + 2] = a.z * SCALAR_SCALE; qv[g * 4 + 3] = a.w * SCALAR_SCALE;
        float4 b = xr4[48 + h * 4 + g];          // ks
        kv[g * 4 + 0] = b.x; kv[g * 4 + 1] = b.y; kv[g * 4 + 2] = b.z; kv[g * 4 + 3] = b.w;
        float4 c = xr4[96 + h * 4 + g];          // vs
        vv[g * 4 + 0] = c.x; vv[g * 4 + 1] = c.y; vv[g * 4 + 2] = c.z; vv[g * 4 + 3] = c.w;
    }
    // point parts
    float qp[12], kp[12], vp[24];
    #pragma unroll
    for (int g = 0; g < 3; ++g) {
        float4 a = xr4[144 + h * 3 + g];
        qp[g * 4 + 0] = a.x; qp[g * 4 + 1] = a.y; qp[g * 4 + 2] = a.z; qp[g * 4 + 3] = a.w;
        float4 b = xr4[180 + h * 3 + g];
        kp[g * 4 + 0] = b.x; kp[g * 4 + 1] = b.y; kp[g * 4 + 2] = b.z; kp[g * 4 + 3] = b.w;
    }
    #pragma unroll
    for (int g = 0; g < 6; ++g) {
        float4 a = xr4[216 + h * 6 + g];
        vp[g * 4 + 0] = a.x; vp[g * 4 + 1] = a.y; vp[g * 4 + 2] = a.z; vp[g * 4 + 3] = a.w;
    }

    float knorm = 0.0f;
    #pragma unroll
    for (int p = 0; p < 4; ++p) {
        #pragma unroll
        for (int i = 0; i < 3; ++i) {
            float qg = R[i * 3] * qp[p * 3] + R[i * 3 + 1] * qp[p * 3 + 1] + R[i * 3 + 2] * qp[p * 3 + 2] + t[i];
            float kg = R[i * 3] * kp[p * 3] + R[i * 3 + 1] * kp[p * 3 + 1] + R[i * 3 + 2] * kp[p * 3 + 2] + t[i];
            qv[16 + p * 3 + i] = spw[p] * qg;
            kv[16 + p * 3 + i] = kg;
            knorm += spw[p] * kg * kg;
        }
    }
    kb[(size_t)h * S + s] = -0.5f * knorm;

    #pragma unroll
    for (int p = 0; p < 8; ++p) {
        #pragma unroll
        for (int i = 0; i < 3; ++i)
            vv[16 + p * 3 + i] = R[i * 3] * vp[p * 3] + R[i * 3 + 1] * vp[p * 3 + 1] + R[i * 3 + 2] * vp[p * 3 + 2] + t[i];
    }

    #pragma unroll
    for (int g = 0; g < 7; ++g)
        Q4[((size_t)h * 7 + g) * S + s] = make_float4(qv[g * 4], qv[g * 4 + 1], qv[g * 4 + 2], qv[g * 4 + 3]);
    #pragma unroll
    for (int g = 0; g < 7; ++g)
        K4[((size_t)h * 7 + g) * S + s] = make_float4(kv[g * 4], kv[g * 4 + 1], kv[g * 4 + 2], kv[g * 4 + 3]);
    #pragma unroll
    for (int g = 0; g < 10; ++g)
        V4[((size_t)h * 10 + g) * S + s] = make_float4(vv[g * 4], vv[g * 4 + 1], vv[g * 4 + 2], vv[g * 4 + 3]);
}

// ---------------------------------------------------------------------------
// Attention: one wave per (h, i).  All loads coalesced float4 (d-major).
// Softmax + PV in-register; 40-wide butterfly reduce; LDS stage (static
// writes) to avoid runtime-indexed register arrays in the epilogue.
// ---------------------------------------------------------------------------
__global__ __launch_bounds__(256)
void ipa_attn(const float4* __restrict__ Q4, const float4* __restrict__ K4,
              const float4* __restrict__ V4, const float* __restrict__ kb,
              const int* __restrict__ valid,
              const float* __restrict__ rot, const float* __restrict__ trans,
              float* __restrict__ combined)
{
    __shared__ float4 sh[4][10];
    const int h = blockIdx.x;
    const int wave = threadIdx.x >> 6;
    const int lane = threadIdx.x & 63;
    const int i = blockIdx.y * 4 + wave;

    // broadcast-load fused query (7 float4)
    float q[DQK];
    #pragma unroll
    for (int g = 0; g < 7; ++g) {
        float4 v = Q4[((size_t)h * 7 + g) * S + i];
        q[g * 4] = v.x; q[g * 4 + 1] = v.y; q[g * 4 + 2] = v.z; q[g * 4 + 3] = v.w;
    }

    const float* kbh = kb + (size_t)h * S;

    float logit[8];
    float mx = -3.0e38f;
    #pragma unroll
    for (int t = 0; t < 8; ++t) {
        int j = t * 64 + lane;
        float dot = kbh[j];
        #pragma unroll
        for (int g = 0; g < 7; ++g) {
            float4 k = K4[((size_t)h * 7 + g) * S + j];
            dot += q[g * 4] * k.x + q[g * 4 + 1] * k.y + q[g * 4 + 2] * k.z + q[g * 4 + 3] * k.w;
        }
        logit[t] = valid[j] ? dot : NEG_LOGIT;
        mx = fmaxf(mx, logit[t]);
    }
    #pragma unroll
    for (int off = 32; off >= 1; off >>= 1)
        mx = fmaxf(mx, __shfl_xor(mx, off, 64));

    float sum = 0.0f;
    #pragma unroll
    for (int t = 0; t < 8; ++t) {
        logit[t] = __expf(logit[t] - mx);
        sum += logit[t];
    }
    #pragma unroll
    for (int off = 32; off >= 1; off >>= 1)
        sum += __shfl_xor(sum, off, 64);
    const float inv = 1.0f / sum;

    // PV accumulate (unnormalized)
    float4 acc[10];
    #pragma unroll
    for (int g = 0; g < 10; ++g) acc[g] = make_float4(0.f, 0.f, 0.f, 0.f);
    #pragma unroll
    for (int t = 0; t < 8; ++t) {
        int j = t * 64 + lane;
        float p = logit[t];
        #pragma unroll
        for (int g = 0; g < 10; ++g) {
            float4 v = V4[((size_t)h * 10 + g) * S + j];
            acc[g].x += p * v.x; acc[g].y += p * v.y;
            acc[g].z += p * v.z; acc[g].w += p * v.w;
        }
    }
    #pragma unroll
    for (int g = 0; g < 10; ++g) {
        #pragma unroll
        for (int off = 32; off >= 1; off >>= 1) {
            acc[g].x += __shfl_xor(acc[g].x, off, 64);
            acc[g].y += __shfl_xor(acc[g].y, off, 64);
            acc[g].z += __shfl_xor(acc[g].z, off, 64);
            acc[g].w += __shfl_xor(acc[g].w, off, 64);
        }
    }

    // stage to LDS with static indices; read back with dynamic (LDS ok)
    if (lane == 0) {
        #pragma unroll
        for (int g = 0; g < 10; ++g) sh[wave][g] = acc[g];
    }
    const float* shf = (const float*)sh[wave];

    float* crow = combined + (size_t)i * 576;
    if (lane < 16)
        crow[h * 16 + lane] = shf[lane] * inv;

    if (lane < 8) {
        float R[9], t_[3];
        #pragma unroll
        for (int a = 0; a < 9; ++a) R[a] = rot[i * 9 + a];
        #pragma unroll
        for (int a = 0; a < 3; ++a) t_[a] = trans[i * 3 + a];
        int p = lane;
        float d0 = shf[16 + p * 3 + 0] * inv - t_[0];
        float d1 = shf[16 + p * 3 + 1] * inv - t_[1];
        float d2 = shf[16 + p * 3 + 2] * inv - t_[2];
        float pol0 = R[0] * d0 + R[3] * d1 + R[6] * d2;
        float pol1 = R[1] * d0 + R[4] * d1 + R[7] * d2;
        float pol2 = R[2] * d0 + R[5] * d1 + R[8] * d2;
        crow[192 + h * 24 + p * 3 + 0] = pol0;
        crow[192 + h * 24 + p * 3 + 1] = pol1;
        crow[192 + h * 24 + p * 3 + 2] = pol2;
        crow[480 + h * 8 + p] = sqrtf(pol0 * pol0 + pol1 * pol1 + pol2 * pol2);
    }
}

// ---------------------------------------------------------------------------
extern "C" void kernel_launch(void* const* d_in, const int* in_sizes, int n_in,
                              void* d_out, int out_size, void* d_ws, size_t ws_size,
                              hipStream_t stream)
{
    const float* single = (const float*)d_in[0];
    const float* rot    = (const float*)d_in[1];
    const float* trans  = (const float*)d_in[2];
    const float* Wq_s   = (const float*)d_in[3];
    const float* bq_s   = (const float*)d_in[4];
    const float* Wk_s   = (const float*)d_in[5];
    const float* bk_s   = (const float*)d_in[6];
    const float* Wv_s   = (const float*)d_in[7];
    const float* bv_s   = (const float*)d_in[8];
    const float* Wq_p   = (const float*)d_in[9];
    const float* bq_p   = (const float*)d_in[10];
    const float* Wk_p   = (const float*)d_in[11];
    const float* bk_p   = (const float*)d_in[12];
    const float* Wv_p   = (const float*)d_in[13];
    const float* bv_p   = (const float*)d_in[14];
    const float* pw     = (const float*)d_in[15];
    const float* Wo     = (const float*)d_in[16];
    const float* bo     = (const float*)d_in[17];
    const int*   valid  = (const int*)d_in[18];

    float* ws = (float*)d_ws;
    float* Wcat     = ws;                                  // 384*1152
    float* bcat     = Wcat + (size_t)384 * XCOLS;          // 1152
    float* X        = bcat + XCOLS;                        // 512*1152
    float* Q4f      = X + (size_t)S * XCOLS;               // 12*7*512*4
    float* K4f      = Q4f + (size_t)H * 7 * S * 4;
    float* V4f      = K4f + (size_t)H * 7 * S * 4;         // 12*10*512*4
    float* kbb      = V4f + (size_t)H * 10 * S * 4;        // 12*512
    float* combined = kbb + (size_t)H * S;                 // 512*576

    dim3 blk(256);

    // 1. weight concat (one float4 per thread)
    wcat_kernel<<<dim3((384 * (XCOLS / 4) + XCOLS / 4 + 255) / 256), blk, 0, stream>>>(
        Wq_s, bq_s, Wk_s, bk_s, Wv_s, bv_s, Wq_p, bq_p, Wk_p, bk_p, Wv_p, bv_p, Wcat, bcat);

    // 2. single fused projection GEMM: X = single @ Wcat + bcat  (512x1152x384)
    gemm64<<<dim3(XCOLS / 64, S / 64), blk, 0, stream>>>(single, C, Wcat, XCOLS, bcat, X, XCOLS, C);

    // 3. fused Q/K/V build (rotations applied, d-major float4 layout)
    ipa_points<<<dim3(S * H / 256), blk, 0, stream>>>(X, rot, trans, pw,
                                                      (float4*)Q4f, (float4*)K4f, (float4*)V4f, kbb);

    // 4. attention -> combined
    ipa_attn<<<dim3(H, S / 4), blk, 0, stream>>>((const float4*)Q4f, (const float4*)K4f,
                                                 (const float4*)V4f, kbb, valid, rot, trans, combined);

    // 5. output projection with query-row masking (32x32 tiles for parallelism)
    gemm_out<<<dim3(C / 32, S / 32), blk, 0, stream>>>(combined, 576, Wo, C, bo, (float*)d_out, C, 576, valid);
}